// Round 1
// baseline (961.861 us; speedup 1.0000x reference)
//
#include <hip/hip_runtime.h>

typedef unsigned short u16;
typedef __bf16 bf16x8 __attribute__((ext_vector_type(8)));
typedef float f32x4 __attribute__((ext_vector_type(4)));
typedef unsigned short us8 __attribute__((ext_vector_type(8)));

#define MFMA(a,b,c) __builtin_amdgcn_mfma_f32_16x16x32_bf16((a),(b),(c),0,0,0)
#define DEV __device__ __forceinline__

DEV u16 f2bf(float f){
  unsigned u = __float_as_uint(f);
  u += 0x7fffu + ((u >> 16) & 1u);
  return (u16)(u >> 16);
}
DEV float silu_f(float v){ return v / (1.f + __expf(-v)); }

// ---------------- weight conversion / repack ----------------
// segments: w1 | w2 | wif | conv_w tau=2 | conv_w tau=3 | wqk^T | wv^T
__global__ void prep_kernel(const float* __restrict__ w1, const float* __restrict__ w2,
                            const float* __restrict__ wif, const float* __restrict__ conv_w,
                            const float* __restrict__ wqk, const float* __restrict__ wv,
                            u16* __restrict__ w1b, u16* __restrict__ w2b, u16* __restrict__ wifb,
                            u16* __restrict__ cw2, u16* __restrict__ cw3,
                            u16* __restrict__ wqkt, u16* __restrict__ wvt)
{
  const long N0 = 4194304;
  const long N1 = N0 + 2097152;
  const long N2 = N1 + 98304;
  const long N3 = N2 + 4194304;
  const long N4 = N3 + 4194304;
  const long N5 = N4 + 1048576;
  const long N6 = N5 + 524288;
  long stride = (long)gridDim.x * blockDim.x;
  for (long i = (long)blockIdx.x*blockDim.x + threadIdx.x; i < N6; i += stride) {
    if (i < N0)      { w1b[i] = f2bf(w1[i]); }
    else if (i < N1) { long j = i-N0; w2b[j] = f2bf(w2[j]); }
    else if (i < N2) { long j = i-N1; wifb[j] = f2bf(wif[j]); }
    else if (i < N3) { long j = i-N2; cw2[j] = f2bf(conv_w[j*4+2]); }
    else if (i < N4) { long j = i-N3; cw3[j] = f2bf(conv_w[j*4+3]); }
    else if (i < N5) { long j = i-N4; long h=j>>17, r=j&131071, o=r>>8, ii=r&255;
                       wqkt[j] = f2bf(wqk[h*131072 + ii*512 + o]); }
    else             { long j = i-N5; long h=j>>16, o=(j>>8)&255, ii=j&255;
                       wvt[j] = f2bf(wv[h*65536 + ii*256 + o]); }
  }
}

// ---------------- input LayerNorm -> bf16 ----------------
__global__ __launch_bounds__(256) void ln_kernel(const float* __restrict__ x,
        const float* __restrict__ w, const float* __restrict__ b, u16* __restrict__ xn)
{
  int row = blockIdx.x, tid = threadIdx.x;
  const float* xr = x + (long)row*1024;
  float4 v = *(const float4*)(xr + tid*4);
  float s = v.x+v.y+v.z+v.w;
  float q = v.x*v.x+v.y*v.y+v.z*v.z+v.w*v.w;
  #pragma unroll
  for (int off=32; off>=1; off>>=1){ s += __shfl_xor(s,off); q += __shfl_xor(q,off); }
  __shared__ float red[8];
  int wv_ = tid>>6;
  if ((tid&63)==0){ red[wv_*2]=s; red[wv_*2+1]=q; }
  __syncthreads();
  s = red[0]+red[2]+red[4]+red[6];
  q = red[1]+red[3]+red[5]+red[7];
  float mu = s*(1.f/1024.f);
  float var = q*(1.f/1024.f) - mu*mu;
  float rs = rsqrtf(var + 1e-5f);
  int c = tid*4;
  u16 o0 = f2bf((v.x-mu)*rs*w[c+0] + b[c+0]);
  u16 o1 = f2bf((v.y-mu)*rs*w[c+1] + b[c+1]);
  u16 o2 = f2bf((v.z-mu)*rs*w[c+2] + b[c+2]);
  u16 o3 = f2bf((v.w-mu)*rs*w[c+3] + b[c+3]);
  uint2 pk;
  pk.x = (unsigned)o0 | ((unsigned)o1<<16);
  pk.y = (unsigned)o2 | ((unsigned)o3<<16);
  *(uint2*)(xn + (long)row*1024 + c) = pk;
}

// ---------------- generic bf16 A(MxK) @ B(NxK)^T GEMM, 128x128 tile ----------------
// epi: 0=raw f32; 1=bf16(acc+bias); 2=GEMM1 split (n<2048 -> x1 bf16, else silu->s2 f32);
//      3=conv final (acc[+prev]+bias, silu, dual f32+bf16); 4=acc+bias+resid(x) -> f32
__global__ __launch_bounds__(256,2) void gemm_bt(
    const u16* __restrict__ A, long lda, long sAz,
    const u16* __restrict__ Bm, long ldb, long sBz,
    const float* __restrict__ bias, long sBiasz,
    int K, int epi,
    float* __restrict__ outf, long ldo,
    u16* __restrict__ outb, long ldob, long sObz,
    const float* __restrict__ prev,
    const float* __restrict__ resid,
    float* __restrict__ outf2)
{
  __shared__ u16 As[128][40];
  __shared__ u16 Bs[128][40];
  int tid = threadIdx.x;
  int bz = blockIdx.z;
  A += (long)bz*sAz; Bm += (long)bz*sBz;
  const float* biasz = bias ? (bias + (long)bz*sBiasz) : bias;
  u16* outbz = outb ? (outb + (long)bz*sObz) : outb;
  long am0 = (long)blockIdx.y*128;
  long bn0 = (long)blockIdx.x*128;
  int lane = tid&63, wave = tid>>6, quad = lane>>4, l15 = lane&15;
  int wm = wave>>1, wn = wave&1;
  int r0 = tid>>2, c8 = (tid&3)*8;
  f32x4 acc[4][4] = {};
  for (int k0=0; k0<K; k0+=32) {
    us8 a0 = *(const us8*)(A + (am0+r0)*lda + k0 + c8);
    us8 a1 = *(const us8*)(A + (am0+r0+64)*lda + k0 + c8);
    us8 b0 = *(const us8*)(Bm + (bn0+r0)*ldb + k0 + c8);
    us8 b1 = *(const us8*)(Bm + (bn0+r0+64)*ldb + k0 + c8);
    __syncthreads();
    *(us8*)&As[r0][c8] = a0;
    *(us8*)&As[r0+64][c8] = a1;
    *(us8*)&Bs[r0][c8] = b0;
    *(us8*)&Bs[r0+64][c8] = b1;
    __syncthreads();
    bf16x8 af[4], bfr[4];
    #pragma unroll
    for (int t=0;t<4;t++){
      af[t]  = *(const bf16x8*)&As[wm*64 + t*16 + l15][quad*8];
      bfr[t] = *(const bf16x8*)&Bs[wn*64 + t*16 + l15][quad*8];
    }
    #pragma unroll
    for (int ti=0;ti<4;ti++)
      #pragma unroll
      for (int tj=0;tj<4;tj++)
        acc[ti][tj] = MFMA(af[ti], bfr[tj], acc[ti][tj]);
  }
  #pragma unroll
  for (int ti=0;ti<4;ti++)
  #pragma unroll
  for (int tj=0;tj<4;tj++)
  #pragma unroll
  for (int r=0;r<4;r++){
    long m = am0 + wm*64 + ti*16 + quad*4 + r;
    long n = bn0 + wn*64 + tj*16 + l15;
    float v = acc[ti][tj][r];
    if (epi==0){ outf[m*ldo+n] = v; }
    else if (epi==1){ outbz[m*ldob+n] = f2bf(v + biasz[n]); }
    else if (epi==2){
      v += biasz[n];
      if (n < 2048) outbz[m*ldob+n] = f2bf(v);
      else outf2[m*2048 + n - 2048] = silu_f(v);
    }
    else if (epi==3){
      if (prev) v += prev[m*ldo+n];
      v += biasz[n]; v = silu_f(v);
      outf[m*ldo+n] = v; outbz[m*ldob+n] = f2bf(v);
    }
    else { outf[m*ldo+n] = v + biasz[n] + resid[m*1024+n]; }
  }
}

// ---------------- gates = qkv @ wif^T (N=16), K-split w/ atomics ----------------
__global__ __launch_bounds__(256) void gates_gemm(const u16* __restrict__ qkv,
        const u16* __restrict__ wifb, float* __restrict__ gates)
{
  int tid = threadIdx.x;
  int lane = tid&63, wave = tid>>6, quad = lane>>4, l15 = lane&15;
  long m0 = (long)blockIdx.x*128 + wave*32;
  int ks = blockIdx.y*1536;
  const u16* arow = qkv + (m0 + l15)*6144;
  const u16* brow = wifb + (long)l15*6144;
  f32x4 acc[2] = {};
  for (int k0=ks; k0<ks+1536; k0+=32){
    bf16x8 a0 = *(const bf16x8*)(arow + k0 + quad*8);
    bf16x8 a1 = *(const bf16x8*)(arow + (long)16*6144 + k0 + quad*8);
    bf16x8 bb = *(const bf16x8*)(brow + k0 + quad*8);
    acc[0] = MFMA(a0,bb,acc[0]);
    acc[1] = MFMA(a1,bb,acc[1]);
  }
  #pragma unroll
  for (int mt=0;mt<2;mt++)
  #pragma unroll
  for (int r=0;r<4;r++)
    atomicAdd(&gates[(m0 + mt*16 + quad*4 + r)*16 + l15], acc[mt][r]);
}

// ---------------- per-(b,h) scan: f_c cumsum, g, running max, exp(-m) ----------------
__global__ void scan_kernel(const float* __restrict__ gates, const float* __restrict__ bif,
        float* __restrict__ g_arr, float* __restrict__ mg_arr, float* __restrict__ enm)
{
  int bh = blockIdx.x; int b = bh>>3, h = bh&7;
  int lane = threadIdx.x;      // 64 threads, 24 l's each
  float bi = bif[h], bff = bif[8+h];
  float fl[24], gl[24];
  int l0 = lane*24;
  float s = 0.f;
  #pragma unroll
  for (int j=0;j<24;j++){
    int l = l0+j;
    float f = gates[((long)(b*1536+l))*16 + 8 + h] + bff;
    float ls = fminf(f,0.f) - log1pf(expf(-fabsf(f)));
    fl[j] = ls; s += ls;
  }
  float tot = s;
  for (int off=1; off<64; off<<=1){ float t = __shfl_up(s, off); if (lane>=off) s += t; }
  float fc = s - tot;          // exclusive prefix
  float lm = -INFINITY;
  #pragma unroll
  for (int j=0;j<24;j++){
    int l = l0+j;
    fc += fl[j];
    fl[j] = fc;                // now cumulative f_c
    float ir = gates[((long)(b*1536+l))*16 + h] + bi;
    float g = expf(ir) - fc;
    gl[j] = g;
    lm = fmaxf(lm, g);
  }
  float im = lm;
  for (int off=1; off<64; off<<=1){ float t = __shfl_up(im, off); if (lane>=off) im = fmaxf(im,t); }
  float ex = __shfl_up(im, 1);
  if (lane==0) ex = -INFINITY;
  float rm = ex;
  #pragma unroll
  for (int j=0;j<24;j++){
    rm = fmaxf(rm, gl[j]);
    long idx = (long)bh*1536 + l0 + j;
    g_arr[idx] = gl[j];
    mg_arr[idx] = rm;
    enm[idx] = expf(-(fl[j] + rm));
  }
}

// ---------------- V -> (b,h,dv,L) global transpose ----------------
__global__ __launch_bounds__(256) void vtrans_kernel(const u16* __restrict__ qkv, u16* __restrict__ vtg)
{
  int l = blockIdx.x*256 + threadIdx.x;
  int bh = blockIdx.y; int b = bh>>3, h = bh&7;
  const u16* src = qkv + ((long)(b*1536+l))*6144 + h*768 + 512;
  u16* dst = vtg + (long)bh*256*1536 + l;
  #pragma unroll
  for (int c=0;c<32;c++){
    us8 v = *(const us8*)(src + c*8);
    #pragma unroll
    for (int j=0;j<8;j++) dst[(long)(c*8+j)*1536] = v[j];
  }
}

// ---------------- decayed attention + head-LN + skip/silu gating -> xm bf16 ----------------
__global__ __launch_bounds__(128,2) void attn_kernel(
    const u16* __restrict__ qkv, const u16* __restrict__ vtg,
    const float* __restrict__ g_arr, const float* __restrict__ mg_arr,
    const float* __restrict__ enm,
    const float* __restrict__ hn_w, const float* __restrict__ skip,
    const float* __restrict__ qkf, const float* __restrict__ s2,
    u16* __restrict__ xm)
{
  __shared__ u16 kt[32][264];      // K tile: 32 i-rows x 256 d
  __shared__ u16 vt[256][40];      // V^T tile: 256 dv x 32 i
  __shared__ u16 pl[2][32][40];    // per-wave P: 32 o x 32 i
  int tid = threadIdx.x;
  int lane = tid&63, wave = tid>>6, quad = lane>>4, l15 = lane&15;
  int bh = blockIdx.y, b = bh>>3, h = bh&7;
  int otile = gridDim.x - 1 - blockIdx.x;    // heavy blocks first
  int o0 = otile*64;
  int ow0 = o0 + wave*32;
  const u16* qbase = qkv + ((long)(b*1536 + ow0 + l15))*6144 + h*768;
  float mg[2][4];
  #pragma unroll
  for (int mt=0;mt<2;mt++)
    #pragma unroll
    for (int r=0;r<4;r++)
      mg[mt][r] = mg_arr[(long)bh*1536 + ow0 + mt*16 + quad*4 + r];
  f32x4 accv[2][16] = {};
  float bs[2][4] = {};
  int nit = 2*(otile+1);
  for (int it=0; it<nit; it++){
    int i0 = it*32;
    __syncthreads();
    #pragma unroll
    for (int s=0;s<8;s++){
      int idx = s*128 + tid;
      int rr = idx>>5, cc = (idx&31)*8;
      *(us8*)&kt[rr][cc] = *(const us8*)(qkv + ((long)(b*1536 + i0 + rr))*6144 + h*768 + 256 + cc);
    }
    #pragma unroll
    for (int s=0;s<8;s++){
      int idx = s*128 + tid;
      int dv = idx>>2, i8 = (idx&3)*8;
      *(us8*)&vt[dv][i8] = *(const us8*)(vtg + ((long)bh*256 + dv)*1536 + i0 + i8);
    }
    __syncthreads();
    // S = Q K^T
    f32x4 sacc[2][2] = {};
    #pragma unroll
    for (int kc=0;kc<8;kc++){
      bf16x8 a0 = *(const bf16x8*)(qbase + kc*32 + quad*8);
      bf16x8 a1 = *(const bf16x8*)(qbase + (long)16*6144 + kc*32 + quad*8);
      bf16x8 b0 = *(const bf16x8*)&kt[l15][kc*32 + quad*8];
      bf16x8 b1 = *(const bf16x8*)&kt[16+l15][kc*32 + quad*8];
      sacc[0][0] = MFMA(a0,b0,sacc[0][0]);
      sacc[0][1] = MFMA(a0,b1,sacc[0][1]);
      sacc[1][0] = MFMA(a1,b0,sacc[1][0]);
      sacc[1][1] = MFMA(a1,b1,sacc[1][1]);
    }
    // P = mask(i<=o) * S/16 * exp(g[i]-maxg[o]); bsum += P; P -> LDS bf16
    #pragma unroll
    for (int nt=0;nt<2;nt++){
      float gi = g_arr[(long)bh*1536 + i0 + nt*16 + l15];
      #pragma unroll
      for (int mt=0;mt<2;mt++)
        #pragma unroll
        for (int r=0;r<4;r++){
          int oi = ow0 + mt*16 + quad*4 + r;
          int ii = i0 + nt*16 + l15;
          float sv = sacc[mt][nt][r]*0.0625f;
          float p = (ii <= oi) ? sv*__expf(gi - mg[mt][r]) : 0.f;
          bs[mt][r] += p;
          pl[wave][mt*16+quad*4+r][nt*16+l15] = f2bf(p);
        }
    }
    // H += P V
    bf16x8 pa0 = *(const bf16x8*)&pl[wave][l15][quad*8];
    bf16x8 pa1 = *(const bf16x8*)&pl[wave][16+l15][quad*8];
    #pragma unroll
    for (int tj=0;tj<16;tj++){
      bf16x8 vb = *(const bf16x8*)&vt[tj*16+l15][quad*8];
      accv[0][tj] = MFMA(pa0, vb, accv[0][tj]);
      accv[1][tj] = MFMA(pa1, vb, accv[1][tj]);
    }
  }
  // epilogue: n = max(|bsum|, exp(-m)); h = acc/n; LN(hn_w); (h + skip*qk)*s2 -> xm
  long browg = (long)b*1536;
  #pragma unroll
  for (int mt=0;mt<2;mt++){
    #pragma unroll
    for (int r=0;r<4;r++){
      int row = ow0 + mt*16 + quad*4 + r;
      float bsum = bs[mt][r];
      #pragma unroll
      for (int off=1; off<16; off<<=1) bsum += __shfl_xor(bsum, off);
      float s1 = 0.f, sq = 0.f;
      #pragma unroll
      for (int tj=0;tj<16;tj++){ float a = accv[mt][tj][r]; s1 += a; sq += a*a; }
      #pragma unroll
      for (int off=1; off<16; off<<=1){ s1 += __shfl_xor(s1,off); sq += __shfl_xor(sq,off); }
      float nv = fmaxf(fabsf(bsum), enm[(long)bh*1536 + row]);
      float inv = 1.f/nv;
      float mu = s1*inv*(1.f/256.f);
      float var = sq*inv*inv*(1.f/256.f) - mu*mu;
      float rs = rsqrtf(var + 1e-5f);
      long rg = browg + row;
      #pragma unroll
      for (int tj=0;tj<16;tj++){
        int col = tj*16 + l15;
        int cc = h*256 + col;
        float y = (accv[mt][tj][r]*inv - mu)*rs*hn_w[col];
        float xv = (y + skip[cc]*qkf[rg*2048 + cc]) * s2[rg*2048 + cc];
        xm[rg*2048 + cc] = f2bf(xv);
      }
    }
  }
}

extern "C" void kernel_launch(void* const* d_in, const int* in_sizes, int n_in,
                              void* d_out, int out_size, void* d_ws, size_t ws_size,
                              hipStream_t stream)
{
  const float* x      = (const float*)d_in[0];
  const float* ln_w   = (const float*)d_in[1];
  const float* ln_b   = (const float*)d_in[2];
  const float* w1     = (const float*)d_in[3];
  const float* b1     = (const float*)d_in[4];
  const float* conv_w = (const float*)d_in[5];
  const float* conv_b = (const float*)d_in[6];
  const float* skip   = (const float*)d_in[7];
  const float* wqk    = (const float*)d_in[8];
  const float* bqk    = (const float*)d_in[9];
  const float* wv     = (const float*)d_in[10];
  const float* bv     = (const float*)d_in[11];
  const float* wif    = (const float*)d_in[12];
  const float* bif    = (const float*)d_in[13];
  const float* hn_w   = (const float*)d_in[14];
  const float* w2     = (const float*)d_in[15];
  const float* b2     = (const float*)d_in[16];
  float* out = (float*)d_out;

  char* p = (char*)d_ws;
  auto alloc = [&](size_t bytes)->void*{ void* r = (void*)p; p += (bytes + 255) & ~(size_t)255; return r; };
  u16* w1b  = (u16*)alloc((size_t)4194304*2);
  u16* w2b  = (u16*)alloc((size_t)2097152*2);
  u16* wifb = (u16*)alloc((size_t)98304*2);
  u16* cw2  = (u16*)alloc((size_t)4194304*2);
  u16* cw3  = (u16*)alloc((size_t)4194304*2);
  u16* wqkt = (u16*)alloc((size_t)1048576*2);
  u16* wvt  = (u16*)alloc((size_t)524288*2);
  u16* xn   = (u16*)alloc((size_t)3072*1024*2);
  u16* x1b  = (u16*)alloc((size_t)3072*2048*2);
  float* s2 = (float*)alloc((size_t)3072*2048*4);
  float* qkf= (float*)alloc((size_t)3072*2048*4);
  u16* qkb  = (u16*)alloc((size_t)3072*2048*2);
  u16* qkv  = (u16*)alloc((size_t)3072*6144*2);
  u16* vtg  = (u16*)alloc((size_t)16*256*1536*2);
  float* gates = (float*)alloc((size_t)3072*16*4);
  float* g_arr = (float*)alloc((size_t)16*1536*4);
  float* mg_arr= (float*)alloc((size_t)16*1536*4);
  float* enm   = (float*)alloc((size_t)16*1536*4);
  u16* xmb  = (u16*)alloc((size_t)3072*2048*2);
  if ((size_t)(p - (char*)d_ws) > ws_size) return;  // ws too small -> visible failure

  hipMemsetAsync(gates, 0, (size_t)3072*16*4, stream);
  prep_kernel<<<4096, 256, 0, stream>>>(w1, w2, wif, conv_w, wqk, wv,
                                        w1b, w2b, wifb, cw2, cw3, wqkt, wvt);
  ln_kernel<<<3072, 256, 0, stream>>>(x, ln_w, ln_b, xn);
  // y = LN(x) @ w1^T + b1 ; split -> x1 (bf16), s2 = silu(x2) (f32)
  gemm_bt<<<dim3(32,24,1), 256, 0, stream>>>(xn, 1024, 0, w1b, 1024, 0, b1, 0, 1024, 2,
       nullptr, 0, x1b, 2048, 0, nullptr, nullptr, s2);
  // conv b=0: silu(x1_0 @ cw3^T + conv_b)
  gemm_bt<<<dim3(16,12,1), 256, 0, stream>>>(x1b, 2048, 0, cw3, 2048, 0, conv_b, 0, 2048, 3,
       qkf, 2048, qkb, 2048, 0, nullptr, nullptr, nullptr);
  // conv b=1 partial: x1_0 @ cw2^T (raw)
  gemm_bt<<<dim3(16,12,1), 256, 0, stream>>>(x1b, 2048, 0, cw2, 2048, 0, nullptr, 0, 2048, 0,
       qkf + (long)1536*2048, 2048, nullptr, 0, 0, nullptr, nullptr, nullptr);
  // conv b=1 final: + x1_1 @ cw3^T + conv_b, silu
  gemm_bt<<<dim3(16,12,1), 256, 0, stream>>>(x1b + (long)1536*2048, 2048, 0, cw3, 2048, 0, conv_b, 0, 2048, 3,
       qkf + (long)1536*2048, 2048, qkb + (long)1536*2048, 2048, 0,
       qkf + (long)1536*2048, nullptr, nullptr);
  // per-head q,k projection -> qkv[.., h*768 + 0..511]
  gemm_bt<<<dim3(4,24,8), 256, 0, stream>>>(qkb, 2048, 256, wqkt, 256, 131072, bqk, 512, 256, 1,
       nullptr, 0, qkv, 6144, 768, nullptr, nullptr, nullptr);
  // per-head v projection -> qkv[.., h*768 + 512..767]
  gemm_bt<<<dim3(2,24,8), 256, 0, stream>>>(x1b, 2048, 256, wvt, 256, 65536, bv, 256, 256, 1,
       nullptr, 0, qkv + 512, 6144, 768, nullptr, nullptr, nullptr);
  vtrans_kernel<<<dim3(6,16,1), 256, 0, stream>>>(qkv, vtg);
  gates_gemm<<<dim3(24,4,1), 256, 0, stream>>>(qkv, wifb, gates);
  scan_kernel<<<16, 64, 0, stream>>>(gates, bif, g_arr, mg_arr, enm);
  attn_kernel<<<dim3(24,16,1), 128, 0, stream>>>(qkv, vtg, g_arr, mg_arr, enm,
       hn_w, skip, qkf, s2, xmb);
  // out = xm @ w2^T + b2 + x
  gemm_bt<<<dim3(8,24,1), 256, 0, stream>>>(xmb, 2048, 0, w2b, 2048, 0, b2, 0, 2048, 4,
       out, 1024, nullptr, 0, 0, nullptr, x, nullptr);
}

// Round 2
// 925.168 us; speedup vs baseline: 1.0397x; 1.0397x over previous
//
#include <hip/hip_runtime.h>

typedef unsigned short u16;
typedef __bf16 bf16x8 __attribute__((ext_vector_type(8)));
typedef float f32x4 __attribute__((ext_vector_type(4)));
typedef unsigned short us8 __attribute__((ext_vector_type(8)));

#define MFMA(a,b,c) __builtin_amdgcn_mfma_f32_16x16x32_bf16((a),(b),(c),0,0,0)
#define DEV __device__ __forceinline__

DEV u16 f2bf(float f){
  unsigned u = __float_as_uint(f);
  u += 0x7fffu + ((u >> 16) & 1u);
  return (u16)(u >> 16);
}
DEV float silu_f(float v){ return v / (1.f + __expf(-v)); }
DEV bf16x8 asbf(us8 v){ return __builtin_bit_cast(bf16x8, v); }
DEV void gl16(const u16* g, u16* l){
  __builtin_amdgcn_global_load_lds((const __attribute__((address_space(1))) void*)g,
                                   (__attribute__((address_space(3))) void*)l, 16, 0, 0);
}

// ---------------- weight conversion / repack ----------------
__global__ void prep_kernel(const float* __restrict__ w1, const float* __restrict__ w2,
                            const float* __restrict__ wif, const float* __restrict__ conv_w,
                            const float* __restrict__ wqk, const float* __restrict__ wv,
                            u16* __restrict__ w1b, u16* __restrict__ w2b, u16* __restrict__ wifb,
                            u16* __restrict__ cw2, u16* __restrict__ cw3,
                            u16* __restrict__ wqkt, u16* __restrict__ wvt)
{
  const long N0 = 4194304;
  const long N1 = N0 + 2097152;
  const long N2 = N1 + 98304;
  const long N3 = N2 + 4194304;
  const long N4 = N3 + 4194304;
  const long N5 = N4 + 1048576;
  const long N6 = N5 + 524288;
  long stride = (long)gridDim.x * blockDim.x;
  for (long i = (long)blockIdx.x*blockDim.x + threadIdx.x; i < N6; i += stride) {
    if (i < N0)      { w1b[i] = f2bf(w1[i]); }
    else if (i < N1) { long j = i-N0; w2b[j] = f2bf(w2[j]); }
    else if (i < N2) { long j = i-N1; wifb[j] = f2bf(wif[j]); }
    else if (i < N3) { long j = i-N2; cw2[j] = f2bf(conv_w[j*4+2]); }
    else if (i < N4) { long j = i-N3; cw3[j] = f2bf(conv_w[j*4+3]); }
    else if (i < N5) { long j = i-N4; long h=j>>17, r=j&131071, o=r>>8, ii=r&255;
                       wqkt[j] = f2bf(wqk[h*131072 + ii*512 + o]); }
    else             { long j = i-N5; long h=j>>16, o=(j>>8)&255, ii=j&255;
                       wvt[j] = f2bf(wv[h*65536 + ii*256 + o]); }
  }
}

// ---------------- input LayerNorm -> bf16 ----------------
__global__ __launch_bounds__(256) void ln_kernel(const float* __restrict__ x,
        const float* __restrict__ w, const float* __restrict__ b, u16* __restrict__ xn)
{
  int row = blockIdx.x, tid = threadIdx.x;
  const float* xr = x + (long)row*1024;
  float4 v = *(const float4*)(xr + tid*4);
  float s = v.x+v.y+v.z+v.w;
  float q = v.x*v.x+v.y*v.y+v.z*v.z+v.w*v.w;
  #pragma unroll
  for (int off=32; off>=1; off>>=1){ s += __shfl_xor(s,off); q += __shfl_xor(q,off); }
  __shared__ float red[8];
  int wv_ = tid>>6;
  if ((tid&63)==0){ red[wv_*2]=s; red[wv_*2+1]=q; }
  __syncthreads();
  s = red[0]+red[2]+red[4]+red[6];
  q = red[1]+red[3]+red[5]+red[7];
  float mu = s*(1.f/1024.f);
  float var = q*(1.f/1024.f) - mu*mu;
  float rs = rsqrtf(var + 1e-5f);
  int c = tid*4;
  u16 o0 = f2bf((v.x-mu)*rs*w[c+0] + b[c+0]);
  u16 o1 = f2bf((v.y-mu)*rs*w[c+1] + b[c+1]);
  u16 o2 = f2bf((v.z-mu)*rs*w[c+2] + b[c+2]);
  u16 o3 = f2bf((v.w-mu)*rs*w[c+3] + b[c+3]);
  uint2 pk;
  pk.x = (unsigned)o0 | ((unsigned)o1<<16);
  pk.y = (unsigned)o2 | ((unsigned)o3<<16);
  *(uint2*)(xn + (long)row*1024 + c) = pk;
}

// ---------------- generic bf16 A(MxK) @ B(NxK)^T GEMM, 128x128 tile ----------------
// global_load_lds staging (width 16), fragment-major LDS layout [rowgrp][quad][l15][8].
// Dual-K: k0<K1 uses (A,Bm), else (A2,B2) at k0-K1 (z must be 1 in dual mode).
// epi: 1=bf16(acc+bias); 2=GEMM1 split (n<2048 -> x1 bf16, else silu->s2 f32);
//      3=conv (acc+bias, silu, dual f32+bf16); 4=acc+bias+resid(x) -> f32
__global__ __launch_bounds__(256,2) void gemm_bt(
    const u16* __restrict__ A, long lda, long sAz,
    const u16* __restrict__ A2,
    const u16* __restrict__ Bm, long ldb, long sBz,
    const u16* __restrict__ B2,
    int K1, int Ktot,
    const float* __restrict__ bias, long sBiasz,
    int epi,
    float* __restrict__ outf, long ldo,
    u16* __restrict__ outb, long ldob, long sObz,
    const float* __restrict__ resid,
    float* __restrict__ outf2)
{
  __shared__ u16 AsF[4096];   // [rg 8][quad 4][l15 16][8]
  __shared__ u16 BsF[4096];
  int tid = threadIdx.x;
  int bz = blockIdx.z;
  A += (long)bz*sAz; Bm += (long)bz*sBz;
  const float* biasz = bias ? (bias + (long)bz*sBiasz) : bias;
  u16* outbz = outb ? (outb + (long)bz*sObz) : outb;
  long am0 = (long)blockIdx.y*128;
  long bn0 = (long)blockIdx.x*128;
  int lane = tid&63, wave = tid>>6, quad = lane>>4, l15 = lane&15;
  int wm = wave>>1, wn = wave&1;
  int kq8 = quad*8;
  f32x4 acc[4][4] = {};
  for (int k0=0; k0<Ktot; k0+=32) {
    const u16* Ak = A; const u16* Bk = Bm; int kk = k0;
    if (k0 >= K1){ Ak = A2; Bk = B2; kk = k0 - K1; }
    __syncthreads();
    gl16(Ak + (am0 + wave*16 + l15)*lda + kk + kq8,       AsF + wave*512);
    gl16(Ak + (am0 + (wave+4)*16 + l15)*lda + kk + kq8,   AsF + (wave+4)*512);
    gl16(Bk + (bn0 + wave*16 + l15)*ldb + kk + kq8,       BsF + wave*512);
    gl16(Bk + (bn0 + (wave+4)*16 + l15)*ldb + kk + kq8,   BsF + (wave+4)*512);
    __syncthreads();
    bf16x8 af[4], bfr[4];
    #pragma unroll
    for (int t=0;t<4;t++){
      af[t]  = *(const bf16x8*)&AsF[(wm*4+t)*512 + quad*128 + l15*8];
      bfr[t] = *(const bf16x8*)&BsF[(wn*4+t)*512 + quad*128 + l15*8];
    }
    #pragma unroll
    for (int ti=0;ti<4;ti++)
      #pragma unroll
      for (int tj=0;tj<4;tj++)
        acc[ti][tj] = MFMA(af[ti], bfr[tj], acc[ti][tj]);
  }
  #pragma unroll
  for (int ti=0;ti<4;ti++)
  #pragma unroll
  for (int tj=0;tj<4;tj++)
  #pragma unroll
  for (int r=0;r<4;r++){
    long m = am0 + wm*64 + ti*16 + quad*4 + r;
    long n = bn0 + wn*64 + tj*16 + l15;
    float v = acc[ti][tj][r];
    if (epi==1){ outbz[m*ldob+n] = f2bf(v + biasz[n]); }
    else if (epi==2){
      v += biasz[n];
      if (n < 2048) outbz[m*ldob+n] = f2bf(v);
      else outf2[m*2048 + n - 2048] = silu_f(v);
    }
    else if (epi==3){
      v += biasz[n]; v = silu_f(v);
      outf[m*ldo+n] = v; outbz[m*ldob+n] = f2bf(v);
    }
    else { outf[m*ldo+n] = v + biasz[n] + resid[m*1024+n]; }
  }
}

// ---------------- gates = qkv @ wif^T (N=16), K-split w/ atomics ----------------
__global__ __launch_bounds__(256) void gates_gemm(const u16* __restrict__ qkv,
        const u16* __restrict__ wifb, float* __restrict__ gates)
{
  int tid = threadIdx.x;
  int lane = tid&63, wave = tid>>6, quad = lane>>4, l15 = lane&15;
  long m0 = (long)blockIdx.x*128 + wave*32;
  int ks = blockIdx.y*1536;
  const u16* arow = qkv + (m0 + l15)*6144;
  const u16* brow = wifb + (long)l15*6144;
  f32x4 acc[2] = {};
  for (int k0=ks; k0<ks+1536; k0+=32){
    bf16x8 a0 = *(const bf16x8*)(arow + k0 + quad*8);
    bf16x8 a1 = *(const bf16x8*)(arow + (long)16*6144 + k0 + quad*8);
    bf16x8 bb = *(const bf16x8*)(brow + k0 + quad*8);
    acc[0] = MFMA(a0,bb,acc[0]);
    acc[1] = MFMA(a1,bb,acc[1]);
  }
  #pragma unroll
  for (int mt=0;mt<2;mt++)
  #pragma unroll
  for (int r=0;r<4;r++)
    atomicAdd(&gates[(m0 + mt*16 + quad*4 + r)*16 + l15], acc[mt][r]);
}

// ---------------- per-(b,h) scan ----------------
__global__ void scan_kernel(const float* __restrict__ gates, const float* __restrict__ bif,
        float* __restrict__ g_arr, float* __restrict__ mg_arr, float* __restrict__ enm)
{
  int bh = blockIdx.x; int b = bh>>3, h = bh&7;
  int lane = threadIdx.x;
  float bi = bif[h], bff = bif[8+h];
  float fl[24], gl[24];
  int l0 = lane*24;
  float s = 0.f;
  #pragma unroll
  for (int j=0;j<24;j++){
    int l = l0+j;
    float f = gates[((long)(b*1536+l))*16 + 8 + h] + bff;
    float ls = fminf(f,0.f) - log1pf(expf(-fabsf(f)));
    fl[j] = ls; s += ls;
  }
  float tot = s;
  for (int off=1; off<64; off<<=1){ float t = __shfl_up(s, off); if (lane>=off) s += t; }
  float fc = s - tot;
  float lm = -INFINITY;
  #pragma unroll
  for (int j=0;j<24;j++){
    int l = l0+j;
    fc += fl[j];
    fl[j] = fc;
    float ir = gates[((long)(b*1536+l))*16 + h] + bi;
    float g = expf(ir) - fc;
    gl[j] = g;
    lm = fmaxf(lm, g);
  }
  float im = lm;
  for (int off=1; off<64; off<<=1){ float t = __shfl_up(im, off); if (lane>=off) im = fmaxf(im,t); }
  float ex = __shfl_up(im, 1);
  if (lane==0) ex = -INFINITY;
  float rm = ex;
  #pragma unroll
  for (int j=0;j<24;j++){
    rm = fmaxf(rm, gl[j]);
    long idx = (long)bh*1536 + l0 + j;
    g_arr[idx] = gl[j];
    mg_arr[idx] = rm;
    enm[idx] = expf(-(fl[j] + rm));
  }
}

// ---------------- V -> (b,h,dv,L) global transpose ----------------
__global__ __launch_bounds__(256) void vtrans_kernel(const u16* __restrict__ qkv, u16* __restrict__ vtg)
{
  int l = blockIdx.x*256 + threadIdx.x;
  int bh = blockIdx.y; int b = bh>>3, h = bh&7;
  const u16* src = qkv + ((long)(b*1536+l))*6144 + h*768 + 512;
  u16* dst = vtg + (long)bh*256*1536 + l;
  #pragma unroll
  for (int c=0;c<32;c++){
    us8 v = *(const us8*)(src + c*8);
    #pragma unroll
    for (int j=0;j<8;j++) dst[(long)(c*8+j)*1536] = v[j];
  }
}

// ---------------- decayed attention: 1 wave per 32-row o-tile, barrier-free ----------------
// grid (16 bh, 48 otiles). Direct global fragment loads (L2), Q preloaded in regs.
__global__ __launch_bounds__(64) void attn_kernel(
    const u16* __restrict__ qkv, const u16* __restrict__ vtg,
    const float* __restrict__ g_arr, const float* __restrict__ mg_arr,
    const float* __restrict__ enm,
    const float* __restrict__ hn_w, const float* __restrict__ skip,
    const float* __restrict__ qkf, const float* __restrict__ s2,
    u16* __restrict__ xm)
{
  __shared__ u16 pl[32][40];
  int lane = threadIdx.x;
  int quad = lane>>4, l15 = lane&15;
  int bh = blockIdx.x, b = bh>>3, h = bh&7;
  int otile = 47 - blockIdx.y;               // heavy-first
  int ow0 = otile*32;
  // Q preload: 32 rows x 256 d -> 16 us8 (64 VGPR)
  us8 qreg[2][8];
  #pragma unroll
  for (int mt=0;mt<2;mt++)
    #pragma unroll
    for (int kc=0;kc<8;kc++)
      qreg[mt][kc] = *(const us8*)(qkv + ((long)(b*1536 + ow0 + mt*16 + l15))*6144 + h*768 + kc*32 + quad*8);
  float mg[2][4];
  #pragma unroll
  for (int mt=0;mt<2;mt++)
    #pragma unroll
    for (int r=0;r<4;r++)
      mg[mt][r] = mg_arr[(long)bh*1536 + ow0 + mt*16 + quad*4 + r];
  f32x4 accv[2][16] = {};
  float bs[2][4] = {};
  int nit = otile + 1;
  for (int it=0; it<nit; it++){
    int i0 = it*32;
    // S = Q K^T  (K fragments direct from global)
    const u16* kbase = qkv + ((long)(b*1536 + i0))*6144 + h*768 + 256;
    f32x4 sacc[2][2] = {};
    #pragma unroll
    for (int kc=0;kc<8;kc++){
      bf16x8 b0 = *(const bf16x8*)(kbase + (long)l15*6144 + kc*32 + quad*8);
      bf16x8 b1 = *(const bf16x8*)(kbase + (long)(16+l15)*6144 + kc*32 + quad*8);
      sacc[0][0] = MFMA(asbf(qreg[0][kc]), b0, sacc[0][0]);
      sacc[0][1] = MFMA(asbf(qreg[0][kc]), b1, sacc[0][1]);
      sacc[1][0] = MFMA(asbf(qreg[1][kc]), b0, sacc[1][0]);
      sacc[1][1] = MFMA(asbf(qreg[1][kc]), b1, sacc[1][1]);
    }
    // P = mask * S/16 * exp(g[i]-maxg[o]); bsum += P; P -> LDS bf16
    #pragma unroll
    for (int nt=0;nt<2;nt++){
      float gi = g_arr[(long)bh*1536 + i0 + nt*16 + l15];
      #pragma unroll
      for (int mt=0;mt<2;mt++)
        #pragma unroll
        for (int r=0;r<4;r++){
          int oi = ow0 + mt*16 + quad*4 + r;
          int ii = i0 + nt*16 + l15;
          float sv = sacc[mt][nt][r]*0.0625f;
          float p = (ii <= oi) ? sv*__expf(gi - mg[mt][r]) : 0.f;
          bs[mt][r] += p;
          pl[mt*16+quad*4+r][nt*16+l15] = f2bf(p);
        }
    }
    // H += P V   (V^T fragments direct from global)
    bf16x8 pa0 = *(const bf16x8*)&pl[l15][quad*8];
    bf16x8 pa1 = *(const bf16x8*)&pl[16+l15][quad*8];
    #pragma unroll
    for (int tj=0;tj<16;tj++){
      bf16x8 vb = *(const bf16x8*)(vtg + ((long)(bh*256 + tj*16 + l15))*1536 + i0 + quad*8);
      accv[0][tj] = MFMA(pa0, vb, accv[0][tj]);
      accv[1][tj] = MFMA(pa1, vb, accv[1][tj]);
    }
  }
  // epilogue
  long browg = (long)b*1536;
  #pragma unroll
  for (int mt=0;mt<2;mt++){
    #pragma unroll
    for (int r=0;r<4;r++){
      int row = ow0 + mt*16 + quad*4 + r;
      float bsum = bs[mt][r];
      #pragma unroll
      for (int off=1; off<16; off<<=1) bsum += __shfl_xor(bsum, off);
      float s1 = 0.f, sq = 0.f;
      #pragma unroll
      for (int tj=0;tj<16;tj++){ float a = accv[mt][tj][r]; s1 += a; sq += a*a; }
      #pragma unroll
      for (int off=1; off<16; off<<=1){ s1 += __shfl_xor(s1,off); sq += __shfl_xor(sq,off); }
      float nv = fmaxf(fabsf(bsum), enm[(long)bh*1536 + row]);
      float inv = 1.f/nv;
      float mu = s1*inv*(1.f/256.f);
      float var = sq*inv*inv*(1.f/256.f) - mu*mu;
      float rs = rsqrtf(var + 1e-5f);
      long rg = browg + row;
      #pragma unroll
      for (int tj=0;tj<16;tj++){
        int col = tj*16 + l15;
        int cc = h*256 + col;
        float y = (accv[mt][tj][r]*inv - mu)*rs*hn_w[col];
        float xv = (y + skip[cc]*qkf[rg*2048 + cc]) * s2[rg*2048 + cc];
        xm[rg*2048 + cc] = f2bf(xv);
      }
    }
  }
}

extern "C" void kernel_launch(void* const* d_in, const int* in_sizes, int n_in,
                              void* d_out, int out_size, void* d_ws, size_t ws_size,
                              hipStream_t stream)
{
  const float* x      = (const float*)d_in[0];
  const float* ln_w   = (const float*)d_in[1];
  const float* ln_b   = (const float*)d_in[2];
  const float* w1     = (const float*)d_in[3];
  const float* b1     = (const float*)d_in[4];
  const float* conv_w = (const float*)d_in[5];
  const float* conv_b = (const float*)d_in[6];
  const float* skip   = (const float*)d_in[7];
  const float* wqk    = (const float*)d_in[8];
  const float* bqk    = (const float*)d_in[9];
  const float* wv     = (const float*)d_in[10];
  const float* bv     = (const float*)d_in[11];
  const float* wif    = (const float*)d_in[12];
  const float* bif    = (const float*)d_in[13];
  const float* hn_w   = (const float*)d_in[14];
  const float* w2     = (const float*)d_in[15];
  const float* b2     = (const float*)d_in[16];
  float* out = (float*)d_out;

  char* p = (char*)d_ws;
  auto alloc = [&](size_t bytes)->void*{ void* r = (void*)p; p += (bytes + 255) & ~(size_t)255; return r; };
  u16* w1b  = (u16*)alloc((size_t)4194304*2);
  u16* w2b  = (u16*)alloc((size_t)2097152*2);
  u16* wifb = (u16*)alloc((size_t)98304*2);
  u16* cw2  = (u16*)alloc((size_t)4194304*2);
  u16* cw3  = (u16*)alloc((size_t)4194304*2);
  u16* wqkt = (u16*)alloc((size_t)1048576*2);
  u16* wvt  = (u16*)alloc((size_t)524288*2);
  u16* xn   = (u16*)alloc((size_t)3072*1024*2);
  u16* x1b  = (u16*)alloc((size_t)3072*2048*2);
  float* s2 = (float*)alloc((size_t)3072*2048*4);
  float* qkf= (float*)alloc((size_t)3072*2048*4);
  u16* qkb  = (u16*)alloc((size_t)3072*2048*2);
  u16* qkv  = (u16*)alloc((size_t)3072*6144*2);
  u16* vtg  = (u16*)alloc((size_t)16*256*1536*2);
  float* gates = (float*)alloc((size_t)3072*16*4);
  float* g_arr = (float*)alloc((size_t)16*1536*4);
  float* mg_arr= (float*)alloc((size_t)16*1536*4);
  float* enm   = (float*)alloc((size_t)16*1536*4);
  u16* xmb  = (u16*)alloc((size_t)3072*2048*2);
  if ((size_t)(p - (char*)d_ws) > ws_size) return;

  hipMemsetAsync(gates, 0, (size_t)3072*16*4, stream);
  prep_kernel<<<4096, 256, 0, stream>>>(w1, w2, wif, conv_w, wqk, wv,
                                        w1b, w2b, wifb, cw2, cw3, wqkt, wvt);
  ln_kernel<<<3072, 256, 0, stream>>>(x, ln_w, ln_b, xn);
  // y = LN(x) @ w1^T + b1 ; split -> x1 (bf16), s2 = silu(x2) (f32)
  gemm_bt<<<dim3(32,24,1), 256, 0, stream>>>(xn, 1024, 0, nullptr, w1b, 1024, 0, nullptr,
       1024, 1024, b1, 0, 2, nullptr, 0, x1b, 2048, 0, nullptr, s2);
  // conv b=0: silu(x1_0 @ cw3^T + conv_b)
  gemm_bt<<<dim3(16,12,1), 256, 0, stream>>>(x1b, 2048, 0, nullptr, cw3, 2048, 0, nullptr,
       2048, 2048, conv_b, 0, 3, qkf, 2048, qkb, 2048, 0, nullptr, nullptr);
  // conv b=1 fused dual-K: x1_0 @ cw2^T + x1_1 @ cw3^T + conv_b, silu
  gemm_bt<<<dim3(16,12,1), 256, 0, stream>>>(x1b, 2048, 0, x1b + (long)1536*2048,
       cw2, 2048, 0, cw3, 2048, 4096, conv_b, 0, 3,
       qkf + (long)1536*2048, 2048, qkb + (long)1536*2048, 2048, 0, nullptr, nullptr);
  // per-head q,k projection -> qkv[.., h*768 + 0..511]
  gemm_bt<<<dim3(4,24,8), 256, 0, stream>>>(qkb, 2048, 256, nullptr, wqkt, 256, 131072, nullptr,
       256, 256, bqk, 512, 1, nullptr, 0, qkv, 6144, 768, nullptr, nullptr);
  // per-head v projection -> qkv[.., h*768 + 512..767]
  gemm_bt<<<dim3(2,24,8), 256, 0, stream>>>(x1b, 2048, 256, nullptr, wvt, 256, 65536, nullptr,
       256, 256, bv, 256, 1, nullptr, 0, qkv + 512, 6144, 768, nullptr, nullptr);
  vtrans_kernel<<<dim3(6,16,1), 256, 0, stream>>>(qkv, vtg);
  gates_gemm<<<dim3(24,4,1), 256, 0, stream>>>(qkv, wifb, gates);
  scan_kernel<<<16, 64, 0, stream>>>(gates, bif, g_arr, mg_arr, enm);
  attn_kernel<<<dim3(16,48,1), 64, 0, stream>>>(qkv, vtg, g_arr, mg_arr, enm,
       hn_w, skip, qkf, s2, xmb);
  // out = xm @ w2^T + b2 + x
  gemm_bt<<<dim3(8,24,1), 256, 0, stream>>>(xmb, 2048, 0, nullptr, w2b, 2048, 0, nullptr,
       2048, 2048, b2, 0, 4, out, 1024, nullptr, 0, 0, x, nullptr);
}

// Round 3
// 780.869 us; speedup vs baseline: 1.2318x; 1.1848x over previous
//
#include <hip/hip_runtime.h>

typedef unsigned short u16;
typedef __bf16 bf16x8 __attribute__((ext_vector_type(8)));
typedef float f32x4 __attribute__((ext_vector_type(4)));
typedef unsigned short us8 __attribute__((ext_vector_type(8)));

#define MFMA(a,b,c) __builtin_amdgcn_mfma_f32_16x16x32_bf16((a),(b),(c),0,0,0)
#define DEV __device__ __forceinline__

DEV u16 f2bf(float f){
  unsigned u = __float_as_uint(f);
  u += 0x7fffu + ((u >> 16) & 1u);
  return (u16)(u >> 16);
}
DEV float silu_f(float v){ return v / (1.f + __expf(-v)); }
DEV bf16x8 asbf(us8 v){ return __builtin_bit_cast(bf16x8, v); }
DEV void gl16(const u16* g, u16* l){
  __builtin_amdgcn_global_load_lds((const __attribute__((address_space(1))) void*)g,
                                   (__attribute__((address_space(3))) void*)l, 16, 0, 0);
}

// ---------------- weight conversion / repack ----------------
__global__ void prep_kernel(const float* __restrict__ w1, const float* __restrict__ w2,
                            const float* __restrict__ wif, const float* __restrict__ conv_w,
                            const float* __restrict__ wqk, const float* __restrict__ wv,
                            u16* __restrict__ w1b, u16* __restrict__ w2b, u16* __restrict__ wifb,
                            u16* __restrict__ cw2, u16* __restrict__ cw3,
                            u16* __restrict__ wqkt, u16* __restrict__ wvt)
{
  const long N0 = 4194304;
  const long N1 = N0 + 2097152;
  const long N2 = N1 + 98304;
  const long N3 = N2 + 4194304;
  const long N4 = N3 + 4194304;
  const long N5 = N4 + 1048576;
  const long N6 = N5 + 524288;
  long stride = (long)gridDim.x * blockDim.x;
  for (long i = (long)blockIdx.x*blockDim.x + threadIdx.x; i < N6; i += stride) {
    if (i < N0)      { w1b[i] = f2bf(w1[i]); }
    else if (i < N1) { long j = i-N0; w2b[j] = f2bf(w2[j]); }
    else if (i < N2) { long j = i-N1; wifb[j] = f2bf(wif[j]); }
    else if (i < N3) { long j = i-N2; cw2[j] = f2bf(conv_w[j*4+2]); }
    else if (i < N4) { long j = i-N3; cw3[j] = f2bf(conv_w[j*4+3]); }
    else if (i < N5) { long j = i-N4; long h=j>>17, r=j&131071, o=r>>8, ii=r&255;
                       wqkt[j] = f2bf(wqk[h*131072 + ii*512 + o]); }
    else             { long j = i-N5; long h=j>>16, o=(j>>8)&255, ii=j&255;
                       wvt[j] = f2bf(wv[h*65536 + ii*256 + o]); }
  }
}

// ---------------- input LayerNorm -> bf16 ----------------
__global__ __launch_bounds__(256) void ln_kernel(const float* __restrict__ x,
        const float* __restrict__ w, const float* __restrict__ b, u16* __restrict__ xn)
{
  int row = blockIdx.x, tid = threadIdx.x;
  const float* xr = x + (long)row*1024;
  float4 v = *(const float4*)(xr + tid*4);
  float s = v.x+v.y+v.z+v.w;
  float q = v.x*v.x+v.y*v.y+v.z*v.z+v.w*v.w;
  #pragma unroll
  for (int off=32; off>=1; off>>=1){ s += __shfl_xor(s,off); q += __shfl_xor(q,off); }
  __shared__ float red[8];
  int wv_ = tid>>6;
  if ((tid&63)==0){ red[wv_*2]=s; red[wv_*2+1]=q; }
  __syncthreads();
  s = red[0]+red[2]+red[4]+red[6];
  q = red[1]+red[3]+red[5]+red[7];
  float mu = s*(1.f/1024.f);
  float var = q*(1.f/1024.f) - mu*mu;
  float rs = rsqrtf(var + 1e-5f);
  int c = tid*4;
  u16 o0 = f2bf((v.x-mu)*rs*w[c+0] + b[c+0]);
  u16 o1 = f2bf((v.y-mu)*rs*w[c+1] + b[c+1]);
  u16 o2 = f2bf((v.z-mu)*rs*w[c+2] + b[c+2]);
  u16 o3 = f2bf((v.w-mu)*rs*w[c+3] + b[c+3]);
  uint2 pk;
  pk.x = (unsigned)o0 | ((unsigned)o1<<16);
  pk.y = (unsigned)o2 | ((unsigned)o3<<16);
  *(uint2*)(xn + (long)row*1024 + c) = pk;
}

// ---------------- generic bf16 A(MxK) @ B(NxK)^T GEMM, 128x128 tile ----------------
__global__ __launch_bounds__(256,2) void gemm_bt(
    const u16* __restrict__ A, long lda, long sAz,
    const u16* __restrict__ A2,
    const u16* __restrict__ Bm, long ldb, long sBz,
    const u16* __restrict__ B2,
    int K1, int Ktot,
    const float* __restrict__ bias, long sBiasz,
    int epi,
    float* __restrict__ outf, long ldo,
    u16* __restrict__ outb, long ldob, long sObz,
    const float* __restrict__ resid,
    float* __restrict__ outf2)
{
  __shared__ u16 AsF[4096];   // [rg 8][quad 4][l15 16][8]
  __shared__ u16 BsF[4096];
  int tid = threadIdx.x;
  int bz = blockIdx.z;
  A += (long)bz*sAz; Bm += (long)bz*sBz;
  const float* biasz = bias ? (bias + (long)bz*sBiasz) : bias;
  u16* outbz = outb ? (outb + (long)bz*sObz) : outb;
  long am0 = (long)blockIdx.y*128;
  long bn0 = (long)blockIdx.x*128;
  int lane = tid&63, wave = tid>>6, quad = lane>>4, l15 = lane&15;
  int wm = wave>>1, wn = wave&1;
  int kq8 = quad*8;
  f32x4 acc[4][4] = {};
  for (int k0=0; k0<Ktot; k0+=32) {
    const u16* Ak = A; const u16* Bk = Bm; int kk = k0;
    if (k0 >= K1){ Ak = A2; Bk = B2; kk = k0 - K1; }
    __syncthreads();
    gl16(Ak + (am0 + wave*16 + l15)*lda + kk + kq8,       AsF + wave*512);
    gl16(Ak + (am0 + (wave+4)*16 + l15)*lda + kk + kq8,   AsF + (wave+4)*512);
    gl16(Bk + (bn0 + wave*16 + l15)*ldb + kk + kq8,       BsF + wave*512);
    gl16(Bk + (bn0 + (wave+4)*16 + l15)*ldb + kk + kq8,   BsF + (wave+4)*512);
    __syncthreads();
    bf16x8 af[4], bfr[4];
    #pragma unroll
    for (int t=0;t<4;t++){
      af[t]  = *(const bf16x8*)&AsF[(wm*4+t)*512 + quad*128 + l15*8];
      bfr[t] = *(const bf16x8*)&BsF[(wn*4+t)*512 + quad*128 + l15*8];
    }
    #pragma unroll
    for (int ti=0;ti<4;ti++)
      #pragma unroll
      for (int tj=0;tj<4;tj++)
        acc[ti][tj] = MFMA(af[ti], bfr[tj], acc[ti][tj]);
  }
  #pragma unroll
  for (int ti=0;ti<4;ti++)
  #pragma unroll
  for (int tj=0;tj<4;tj++)
  #pragma unroll
  for (int r=0;r<4;r++){
    long m = am0 + wm*64 + ti*16 + quad*4 + r;
    long n = bn0 + wn*64 + tj*16 + l15;
    float v = acc[ti][tj][r];
    if (epi==1){ outbz[m*ldob+n] = f2bf(v + biasz[n]); }
    else if (epi==2){
      v += biasz[n];
      if (n < 2048) outbz[m*ldob+n] = f2bf(v);
      else outf2[m*2048 + n - 2048] = silu_f(v);
    }
    else if (epi==3){
      v += biasz[n]; v = silu_f(v);
      outf[m*ldo+n] = v; outbz[m*ldob+n] = f2bf(v);
    }
    else { outf[m*ldo+n] = v + biasz[n] + resid[m*1024+n]; }
  }
}

// ---------------- gates = qkv @ wif^T (N=16), K-split w/ atomics ----------------
__global__ __launch_bounds__(256) void gates_gemm(const u16* __restrict__ qkv,
        const u16* __restrict__ wifb, float* __restrict__ gates)
{
  int tid = threadIdx.x;
  int lane = tid&63, wave = tid>>6, quad = lane>>4, l15 = lane&15;
  long m0 = (long)blockIdx.x*128 + wave*32;
  int ks = blockIdx.y*1536;
  const u16* arow = qkv + (m0 + l15)*6144;
  const u16* brow = wifb + (long)l15*6144;
  f32x4 acc[2] = {};
  for (int k0=ks; k0<ks+1536; k0+=32){
    bf16x8 a0 = *(const bf16x8*)(arow + k0 + quad*8);
    bf16x8 a1 = *(const bf16x8*)(arow + (long)16*6144 + k0 + quad*8);
    bf16x8 bb = *(const bf16x8*)(brow + k0 + quad*8);
    acc[0] = MFMA(a0,bb,acc[0]);
    acc[1] = MFMA(a1,bb,acc[1]);
  }
  #pragma unroll
  for (int mt=0;mt<2;mt++)
  #pragma unroll
  for (int r=0;r<4;r++)
    atomicAdd(&gates[(m0 + mt*16 + quad*4 + r)*16 + l15], acc[mt][r]);
}

// ---------------- per-(b,h) scan ----------------
__global__ void scan_kernel(const float* __restrict__ gates, const float* __restrict__ bif,
        float* __restrict__ g_arr, float* __restrict__ mg_arr, float* __restrict__ enm)
{
  int bh = blockIdx.x; int b = bh>>3, h = bh&7;
  int lane = threadIdx.x;
  float bi = bif[h], bff = bif[8+h];
  float fl[24], gl[24];
  int l0 = lane*24;
  float s = 0.f;
  #pragma unroll
  for (int j=0;j<24;j++){
    int l = l0+j;
    float f = gates[((long)(b*1536+l))*16 + 8 + h] + bff;
    float ls = fminf(f,0.f) - log1pf(expf(-fabsf(f)));
    fl[j] = ls; s += ls;
  }
  float tot = s;
  for (int off=1; off<64; off<<=1){ float t = __shfl_up(s, off); if (lane>=off) s += t; }
  float fc = s - tot;
  float lm = -INFINITY;
  #pragma unroll
  for (int j=0;j<24;j++){
    int l = l0+j;
    fc += fl[j];
    fl[j] = fc;
    float ir = gates[((long)(b*1536+l))*16 + h] + bi;
    float g = expf(ir) - fc;
    gl[j] = g;
    lm = fmaxf(lm, g);
  }
  float im = lm;
  for (int off=1; off<64; off<<=1){ float t = __shfl_up(im, off); if (lane>=off) im = fmaxf(im,t); }
  float ex = __shfl_up(im, 1);
  if (lane==0) ex = -INFINITY;
  float rm = ex;
  #pragma unroll
  for (int j=0;j<24;j++){
    rm = fmaxf(rm, gl[j]);
    long idx = (long)bh*1536 + l0 + j;
    g_arr[idx] = gl[j];
    mg_arr[idx] = rm;
    enm[idx] = expf(-(fl[j] + rm));
  }
}

// ---------------- V -> (b,h,dv,L) global transpose ----------------
__global__ __launch_bounds__(256) void vtrans_kernel(const u16* __restrict__ qkv, u16* __restrict__ vtg)
{
  int l = blockIdx.x*256 + threadIdx.x;
  int bh = blockIdx.y; int b = bh>>3, h = bh&7;
  const u16* src = qkv + ((long)(b*1536+l))*6144 + h*768 + 512;
  u16* dst = vtg + (long)bh*256*1536 + l;
  #pragma unroll
  for (int c=0;c<32;c++){
    us8 v = *(const us8*)(src + c*8);
    #pragma unroll
    for (int j=0;j<8;j++) dst[(long)(c*8+j)*1536] = v[j];
  }
}

// ---------------- decayed attention: 4 waves share one 32-row o-tile, i-strided ----------------
// grid (16 bh, 48 otiles), 256 threads. Main loop barrier-free; LDS tree-reduce at end.
__global__ __launch_bounds__(256,2) void attn_kernel(
    const u16* __restrict__ qkv, const u16* __restrict__ vtg,
    const float* __restrict__ g_arr, const float* __restrict__ mg_arr,
    const float* __restrict__ enm,
    const float* __restrict__ hn_w, const float* __restrict__ skip,
    const float* __restrict__ qkf, const float* __restrict__ s2,
    u16* __restrict__ xm)
{
  __shared__ u16 pl[4][32][40];
  __shared__ float red[256*36];     // [col][row-pad36], f32x4-aligned
  __shared__ float redb[3][32];
  int tid = threadIdx.x;
  int lane = tid&63, wave = tid>>6, quad = lane>>4, l15 = lane&15;
  int bh = blockIdx.x, b = bh>>3, h = bh&7;
  int otile = 47 - blockIdx.y;               // heavy-first
  int ow0 = otile*32;
  // Q preload: 32 rows x 256 d (per wave; L2-hot)
  us8 qreg[2][8];
  #pragma unroll
  for (int mt=0;mt<2;mt++)
    #pragma unroll
    for (int kc=0;kc<8;kc++)
      qreg[mt][kc] = *(const us8*)(qkv + ((long)(b*1536 + ow0 + mt*16 + l15))*6144 + h*768 + kc*32 + quad*8);
  float mg[2][4];
  #pragma unroll
  for (int mt=0;mt<2;mt++)
    #pragma unroll
    for (int r=0;r<4;r++)
      mg[mt][r] = mg_arr[(long)bh*1536 + ow0 + mt*16 + quad*4 + r];
  f32x4 accv[2][16] = {};
  float bs[2][4] = {};
  for (int it=wave; it<=otile; it+=4){
    int i0 = it*32;
    // S = Q K^T (K fragments direct from global/L2)
    const u16* kbase = qkv + ((long)(b*1536 + i0))*6144 + h*768 + 256;
    f32x4 sacc[2][2] = {};
    #pragma unroll
    for (int kc=0;kc<8;kc++){
      bf16x8 b0 = *(const bf16x8*)(kbase + (long)l15*6144 + kc*32 + quad*8);
      bf16x8 b1 = *(const bf16x8*)(kbase + (long)(16+l15)*6144 + kc*32 + quad*8);
      sacc[0][0] = MFMA(asbf(qreg[0][kc]), b0, sacc[0][0]);
      sacc[0][1] = MFMA(asbf(qreg[0][kc]), b1, sacc[0][1]);
      sacc[1][0] = MFMA(asbf(qreg[1][kc]), b0, sacc[1][0]);
      sacc[1][1] = MFMA(asbf(qreg[1][kc]), b1, sacc[1][1]);
    }
    // P = mask * S/16 * exp(g[i]-maxg[o])
    #pragma unroll
    for (int nt=0;nt<2;nt++){
      float gi = g_arr[(long)bh*1536 + i0 + nt*16 + l15];
      #pragma unroll
      for (int mt=0;mt<2;mt++)
        #pragma unroll
        for (int r=0;r<4;r++){
          int oi = ow0 + mt*16 + quad*4 + r;
          int ii = i0 + nt*16 + l15;
          float sv = sacc[mt][nt][r]*0.0625f;
          float p = (ii <= oi) ? sv*__expf(gi - mg[mt][r]) : 0.f;
          bs[mt][r] += p;
          pl[wave][mt*16+quad*4+r][nt*16+l15] = f2bf(p);
        }
    }
    // H += P V (V^T fragments direct from global/L2)
    bf16x8 pa0 = *(const bf16x8*)&pl[wave][l15][quad*8];
    bf16x8 pa1 = *(const bf16x8*)&pl[wave][16+l15][quad*8];
    #pragma unroll
    for (int tj=0;tj<16;tj++){
      bf16x8 vb = *(const bf16x8*)(vtg + ((long)(bh*256 + tj*16 + l15))*1536 + i0 + quad*8);
      accv[0][tj] = MFMA(pa0, vb, accv[0][tj]);
      accv[1][tj] = MFMA(pa1, vb, accv[1][tj]);
    }
  }
  // lane-reduce bsum over the 16 cols this lane group covers
  #pragma unroll
  for (int mt=0;mt<2;mt++)
    #pragma unroll
    for (int r=0;r<4;r++)
      #pragma unroll
      for (int off=1; off<16; off<<=1) bs[mt][r] += __shfl_xor(bs[mt][r], off);
  // cross-wave tree reduction through LDS
  for (int w=1; w<4; w++){
    if (wave==w){
      #pragma unroll
      for (int mt=0;mt<2;mt++)
        #pragma unroll
        for (int tj=0;tj<16;tj++)
          *(f32x4*)&red[(tj*16+l15)*36 + mt*16 + quad*4] = accv[mt][tj];
      if (l15==0){
        #pragma unroll
        for (int mt=0;mt<2;mt++)
          #pragma unroll
          for (int r=0;r<4;r++)
            redb[w-1][mt*16+quad*4+r] = bs[mt][r];
      }
    }
    __syncthreads();
    if (wave==0){
      #pragma unroll
      for (int mt=0;mt<2;mt++)
        #pragma unroll
        for (int tj=0;tj<16;tj++)
          accv[mt][tj] += *(const f32x4*)&red[(tj*16+l15)*36 + mt*16 + quad*4];
      #pragma unroll
      for (int mt=0;mt<2;mt++)
        #pragma unroll
        for (int r=0;r<4;r++)
          bs[mt][r] += redb[w-1][mt*16+quad*4+r];
    }
    __syncthreads();
  }
  if (wave != 0) return;
  // epilogue: n = max(|bsum|, exp(-m)); h = acc/n; LN(hn_w); (h + skip*qk)*s2 -> xm
  long browg = (long)b*1536;
  #pragma unroll
  for (int mt=0;mt<2;mt++){
    #pragma unroll
    for (int r=0;r<4;r++){
      int row = ow0 + mt*16 + quad*4 + r;
      float s1 = 0.f, sq = 0.f;
      #pragma unroll
      for (int tj=0;tj<16;tj++){ float a = accv[mt][tj][r]; s1 += a; sq += a*a; }
      #pragma unroll
      for (int off=1; off<16; off<<=1){ s1 += __shfl_xor(s1,off); sq += __shfl_xor(sq,off); }
      float nv = fmaxf(fabsf(bs[mt][r]), enm[(long)bh*1536 + row]);
      float inv = 1.f/nv;
      float mu = s1*inv*(1.f/256.f);
      float var = sq*inv*inv*(1.f/256.f) - mu*mu;
      float rs = rsqrtf(var + 1e-5f);
      long rg = browg + row;
      #pragma unroll
      for (int tj=0;tj<16;tj++){
        int col = tj*16 + l15;
        int cc = h*256 + col;
        float y = (accv[mt][tj][r]*inv - mu)*rs*hn_w[col];
        float xv = (y + skip[cc]*qkf[rg*2048 + cc]) * s2[rg*2048 + cc];
        xm[rg*2048 + cc] = f2bf(xv);
      }
    }
  }
}

extern "C" void kernel_launch(void* const* d_in, const int* in_sizes, int n_in,
                              void* d_out, int out_size, void* d_ws, size_t ws_size,
                              hipStream_t stream)
{
  const float* x      = (const float*)d_in[0];
  const float* ln_w   = (const float*)d_in[1];
  const float* ln_b   = (const float*)d_in[2];
  const float* w1     = (const float*)d_in[3];
  const float* b1     = (const float*)d_in[4];
  const float* conv_w = (const float*)d_in[5];
  const float* conv_b = (const float*)d_in[6];
  const float* skip   = (const float*)d_in[7];
  const float* wqk    = (const float*)d_in[8];
  const float* bqk    = (const float*)d_in[9];
  const float* wv     = (const float*)d_in[10];
  const float* bv     = (const float*)d_in[11];
  const float* wif    = (const float*)d_in[12];
  const float* bif    = (const float*)d_in[13];
  const float* hn_w   = (const float*)d_in[14];
  const float* w2     = (const float*)d_in[15];
  const float* b2     = (const float*)d_in[16];
  float* out = (float*)d_out;

  char* p = (char*)d_ws;
  auto alloc = [&](size_t bytes)->void*{ void* r = (void*)p; p += (bytes + 255) & ~(size_t)255; return r; };
  u16* w1b  = (u16*)alloc((size_t)4194304*2);
  u16* w2b  = (u16*)alloc((size_t)2097152*2);
  u16* wifb = (u16*)alloc((size_t)98304*2);
  u16* cw2  = (u16*)alloc((size_t)4194304*2);
  u16* cw3  = (u16*)alloc((size_t)4194304*2);
  u16* wqkt = (u16*)alloc((size_t)1048576*2);
  u16* wvt  = (u16*)alloc((size_t)524288*2);
  u16* xn   = (u16*)alloc((size_t)3072*1024*2);
  u16* x1b  = (u16*)alloc((size_t)3072*2048*2);
  float* s2 = (float*)alloc((size_t)3072*2048*4);
  float* qkf= (float*)alloc((size_t)3072*2048*4);
  u16* qkb  = (u16*)alloc((size_t)3072*2048*2);
  u16* qkv  = (u16*)alloc((size_t)3072*6144*2);
  u16* vtg  = (u16*)alloc((size_t)16*256*1536*2);
  float* gates = (float*)alloc((size_t)3072*16*4);
  float* g_arr = (float*)alloc((size_t)16*1536*4);
  float* mg_arr= (float*)alloc((size_t)16*1536*4);
  float* enm   = (float*)alloc((size_t)16*1536*4);
  u16* xmb  = (u16*)alloc((size_t)3072*2048*2);
  if ((size_t)(p - (char*)d_ws) > ws_size) return;

  hipMemsetAsync(gates, 0, (size_t)3072*16*4, stream);
  prep_kernel<<<4096, 256, 0, stream>>>(w1, w2, wif, conv_w, wqk, wv,
                                        w1b, w2b, wifb, cw2, cw3, wqkt, wvt);
  ln_kernel<<<3072, 256, 0, stream>>>(x, ln_w, ln_b, xn);
  // y = LN(x) @ w1^T + b1 ; split -> x1 (bf16), s2 = silu(x2) (f32)
  gemm_bt<<<dim3(32,24,1), 256, 0, stream>>>(xn, 1024, 0, nullptr, w1b, 1024, 0, nullptr,
       1024, 1024, b1, 0, 2, nullptr, 0, x1b, 2048, 0, nullptr, s2);
  // conv b=0: silu(x1_0 @ cw3^T + conv_b)
  gemm_bt<<<dim3(16,12,1), 256, 0, stream>>>(x1b, 2048, 0, nullptr, cw3, 2048, 0, nullptr,
       2048, 2048, conv_b, 0, 3, qkf, 2048, qkb, 2048, 0, nullptr, nullptr);
  // conv b=1 fused dual-K: x1_0 @ cw2^T + x1_1 @ cw3^T + conv_b, silu
  gemm_bt<<<dim3(16,12,1), 256, 0, stream>>>(x1b, 2048, 0, x1b + (long)1536*2048,
       cw2, 2048, 0, cw3, 2048, 4096, conv_b, 0, 3,
       qkf + (long)1536*2048, 2048, qkb + (long)1536*2048, 2048, 0, nullptr, nullptr);
  // per-head q,k projection -> qkv[.., h*768 + 0..511]
  gemm_bt<<<dim3(4,24,8), 256, 0, stream>>>(qkb, 2048, 256, nullptr, wqkt, 256, 131072, nullptr,
       256, 256, bqk, 512, 1, nullptr, 0, qkv, 6144, 768, nullptr, nullptr);
  // per-head v projection -> qkv[.., h*768 + 512..767]
  gemm_bt<<<dim3(2,24,8), 256, 0, stream>>>(x1b, 2048, 256, nullptr, wvt, 256, 65536, nullptr,
       256, 256, bv, 256, 1, nullptr, 0, qkv + 512, 6144, 768, nullptr, nullptr);
  vtrans_kernel<<<dim3(6,16,1), 256, 0, stream>>>(qkv, vtg);
  gates_gemm<<<dim3(24,4,1), 256, 0, stream>>>(qkv, wifb, gates);
  scan_kernel<<<16, 64, 0, stream>>>(gates, bif, g_arr, mg_arr, enm);
  attn_kernel<<<dim3(16,48,1), 256, 0, stream>>>(qkv, vtg, g_arr, mg_arr, enm,
       hn_w, skip, qkf, s2, xmb);
  // out = xm @ w2^T + b2 + x
  gemm_bt<<<dim3(8,24,1), 256, 0, stream>>>(xmb, 2048, 0, nullptr, w2b, 2048, 0, nullptr,
       2048, 2048, b2, 0, 4, out, 1024, nullptr, 0, 0, x, nullptr);
}

// Round 4
// 653.050 us; speedup vs baseline: 1.4729x; 1.1957x over previous
//
#include <hip/hip_runtime.h>

typedef unsigned short u16;
typedef __bf16 bf16x8 __attribute__((ext_vector_type(8)));
typedef float f32x4 __attribute__((ext_vector_type(4)));
typedef unsigned short us8 __attribute__((ext_vector_type(8)));

#define MFMA(a,b,c) __builtin_amdgcn_mfma_f32_16x16x32_bf16((a),(b),(c),0,0,0)
#define DEV __device__ __forceinline__

DEV u16 f2bf(float f){
  unsigned u = __float_as_uint(f);
  u += 0x7fffu + ((u >> 16) & 1u);
  return (u16)(u >> 16);
}
DEV float bf2f(u16 v){ return __uint_as_float(((unsigned)v)<<16); }
DEV float silu_f(float v){ return v / (1.f + __expf(-v)); }
DEV bf16x8 asbf(us8 v){ return __builtin_bit_cast(bf16x8, v); }

// ---------------- weight conversion / repack ----------------
__global__ void prep_kernel(const float* __restrict__ w1, const float* __restrict__ w2,
                            const float* __restrict__ wif, const float* __restrict__ conv_w,
                            const float* __restrict__ wqk, const float* __restrict__ wv,
                            u16* __restrict__ w1b, u16* __restrict__ w2b, u16* __restrict__ wifb,
                            u16* __restrict__ cw2, u16* __restrict__ cw3,
                            u16* __restrict__ wqkt, u16* __restrict__ wvt)
{
  const long N0 = 4194304;
  const long N1 = N0 + 2097152;
  const long N2 = N1 + 98304;
  const long N3 = N2 + 4194304;          // conv_w taps 2+3 in one pass
  const long N4 = N3 + 1048576;
  const long N5 = N4 + 524288;
  long stride = (long)gridDim.x * blockDim.x;
  for (long i = (long)blockIdx.x*blockDim.x + threadIdx.x; i < N5; i += stride) {
    if (i < N0)      { w1b[i] = f2bf(w1[i]); }
    else if (i < N1) { long j = i-N0; w2b[j] = f2bf(w2[j]); }
    else if (i < N2) { long j = i-N1; wifb[j] = f2bf(wif[j]); }
    else if (i < N3) { long j = i-N2; float2 t = *(const float2*)(conv_w + j*4 + 2);
                       cw2[j] = f2bf(t.x); cw3[j] = f2bf(t.y); }
    else if (i < N4) { long j = i-N3; long h=j>>17, r=j&131071, o=r>>8, ii=r&255;
                       wqkt[j] = f2bf(wqk[h*131072 + ii*512 + o]); }
    else             { long j = i-N4; long h=j>>16, o=(j>>8)&255, ii=j&255;
                       wvt[j] = f2bf(wv[h*65536 + ii*256 + o]); }
  }
}

// ---------------- input LayerNorm -> bf16 ----------------
__global__ __launch_bounds__(256) void ln_kernel(const float* __restrict__ x,
        const float* __restrict__ w, const float* __restrict__ b, u16* __restrict__ xn)
{
  int row = blockIdx.x, tid = threadIdx.x;
  const float* xr = x + (long)row*1024;
  float4 v = *(const float4*)(xr + tid*4);
  float s = v.x+v.y+v.z+v.w;
  float q = v.x*v.x+v.y*v.y+v.z*v.z+v.w*v.w;
  #pragma unroll
  for (int off=32; off>=1; off>>=1){ s += __shfl_xor(s,off); q += __shfl_xor(q,off); }
  __shared__ float red[8];
  int wv_ = tid>>6;
  if ((tid&63)==0){ red[wv_*2]=s; red[wv_*2+1]=q; }
  __syncthreads();
  s = red[0]+red[2]+red[4]+red[6];
  q = red[1]+red[3]+red[5]+red[7];
  float mu = s*(1.f/1024.f);
  float var = q*(1.f/1024.f) - mu*mu;
  float rs = rsqrtf(var + 1e-5f);
  int c = tid*4;
  u16 o0 = f2bf((v.x-mu)*rs*w[c+0] + b[c+0]);
  u16 o1 = f2bf((v.y-mu)*rs*w[c+1] + b[c+1]);
  u16 o2 = f2bf((v.z-mu)*rs*w[c+2] + b[c+2]);
  u16 o3 = f2bf((v.w-mu)*rs*w[c+3] + b[c+3]);
  uint2 pk;
  pk.x = (unsigned)o0 | ((unsigned)o1<<16);
  pk.y = (unsigned)o2 | ((unsigned)o3<<16);
  *(uint2*)(xn + (long)row*1024 + c) = pk;
}

// ---------------- generic bf16 A(MxK) @ B(NxK)^T GEMM, 128x128 tile ----------------
// convmode: gridDim.z=2 config switch — z=0: A@Bm^T (K1); z=1: A@B2^T then A2@Bm^T (Ktot).
// epi: 1=bf16(acc+bias); 2=GEMM1 split; 3=conv (silu, dual f32+bf16); 4=acc+bias+resid -> f32
__global__ __launch_bounds__(256,2) void gemm_bt(
    const u16* __restrict__ A, long lda, long sAz,
    const u16* __restrict__ A2,
    const u16* __restrict__ Bm, long ldb, long sBz,
    const u16* __restrict__ B2,
    int K1, int Ktot, int convmode,
    const float* __restrict__ bias, long sBiasz,
    int epi,
    float* __restrict__ outf, long ldo, long sOfz,
    u16* __restrict__ outb, long ldob, long sObz,
    const float* __restrict__ resid,
    float* __restrict__ outf2)
{
  __shared__ u16 AsF[4096];   // [rg 8][quad 4][l15 16][8]
  __shared__ u16 BsF[4096];
  int tid = threadIdx.x;
  int bz = blockIdx.z;
  A += (long)bz*sAz; Bm += (long)bz*sBz;
  const float* biasz = bias ? (bias + (long)bz*sBiasz) : bias;
  u16* outbz = outb ? (outb + (long)bz*sObz) : outb;
  float* outfz = outf ? (outf + (long)bz*sOfz) : outf;
  long am0 = (long)blockIdx.y*128;
  long bn0 = (long)blockIdx.x*128;
  int lane = tid&63, wave = tid>>6, quad = lane>>4, l15 = lane&15;
  int wm = wave>>1, wn = wave&1;
  int kq8 = quad*8;
  int dual = convmode && (bz==1);
  int Kt = dual ? Ktot : K1;
  f32x4 acc[4][4] = {};
  for (int k0=0; k0<Kt; k0+=32) {
    const u16* Ak; const u16* Bk; int kk;
    if (dual){
      if (k0 < K1){ Ak = A; Bk = B2; kk = k0; }
      else        { Ak = A2; Bk = Bm; kk = k0 - K1; }
    } else { Ak = A; Bk = Bm; kk = k0; }
    __syncthreads();
    __builtin_amdgcn_global_load_lds((const __attribute__((address_space(1))) void*)(Ak + (am0 + wave*16 + l15)*lda + kk + kq8),
                                     (__attribute__((address_space(3))) void*)(AsF + wave*512), 16, 0, 0);
    __builtin_amdgcn_global_load_lds((const __attribute__((address_space(1))) void*)(Ak + (am0 + (wave+4)*16 + l15)*lda + kk + kq8),
                                     (__attribute__((address_space(3))) void*)(AsF + (wave+4)*512), 16, 0, 0);
    __builtin_amdgcn_global_load_lds((const __attribute__((address_space(1))) void*)(Bk + (bn0 + wave*16 + l15)*ldb + kk + kq8),
                                     (__attribute__((address_space(3))) void*)(BsF + wave*512), 16, 0, 0);
    __builtin_amdgcn_global_load_lds((const __attribute__((address_space(1))) void*)(Bk + (bn0 + (wave+4)*16 + l15)*ldb + kk + kq8),
                                     (__attribute__((address_space(3))) void*)(BsF + (wave+4)*512), 16, 0, 0);
    __syncthreads();
    bf16x8 af[4], bfr[4];
    #pragma unroll
    for (int t=0;t<4;t++){
      af[t]  = *(const bf16x8*)&AsF[(wm*4+t)*512 + quad*128 + l15*8];
      bfr[t] = *(const bf16x8*)&BsF[(wn*4+t)*512 + quad*128 + l15*8];
    }
    #pragma unroll
    for (int ti=0;ti<4;ti++)
      #pragma unroll
      for (int tj=0;tj<4;tj++)
        acc[ti][tj] = MFMA(af[ti], bfr[tj], acc[ti][tj]);
  }
  #pragma unroll
  for (int ti=0;ti<4;ti++)
  #pragma unroll
  for (int tj=0;tj<4;tj++)
  #pragma unroll
  for (int r=0;r<4;r++){
    long m = am0 + wm*64 + ti*16 + quad*4 + r;
    long n = bn0 + wn*64 + tj*16 + l15;
    float v = acc[ti][tj][r];
    if (epi==1){ outbz[m*ldob+n] = f2bf(v + biasz[n]); }
    else if (epi==2){
      v += biasz[n];
      if (n < 2048) outbz[m*ldob+n] = f2bf(v);
      else outf2[m*2048 + n - 2048] = silu_f(v);
    }
    else if (epi==3){
      v += biasz[n]; v = silu_f(v);
      outfz[m*ldo+n] = v; outbz[m*ldob+n] = f2bf(v);
    }
    else { outfz[m*ldo+n] = v + biasz[n] + resid[m*1024+n]; }
  }
}

// ---------------- gates = qkv @ wif^T (N=16), K-split w/ atomics ----------------
__global__ __launch_bounds__(256) void gates_gemm(const u16* __restrict__ qkv,
        const u16* __restrict__ wifb, float* __restrict__ gates)
{
  int tid = threadIdx.x;
  int lane = tid&63, wave = tid>>6, quad = lane>>4, l15 = lane&15;
  long m0 = (long)blockIdx.x*128 + wave*32;
  int ks = blockIdx.y*1536;
  const u16* arow = qkv + (m0 + l15)*6144;
  const u16* brow = wifb + (long)l15*6144;
  f32x4 acc[2] = {};
  for (int k0=ks; k0<ks+1536; k0+=32){
    bf16x8 a0 = *(const bf16x8*)(arow + k0 + quad*8);
    bf16x8 a1 = *(const bf16x8*)(arow + (long)16*6144 + k0 + quad*8);
    bf16x8 bb = *(const bf16x8*)(brow + k0 + quad*8);
    acc[0] = MFMA(a0,bb,acc[0]);
    acc[1] = MFMA(a1,bb,acc[1]);
  }
  #pragma unroll
  for (int mt=0;mt<2;mt++)
  #pragma unroll
  for (int r=0;r<4;r++)
    atomicAdd(&gates[(m0 + mt*16 + quad*4 + r)*16 + l15], acc[mt][r]);
}

// ---------------- per-(b,h) scan ----------------
__global__ void scan_kernel(const float* __restrict__ gates, const float* __restrict__ bif,
        float* __restrict__ g_arr, float* __restrict__ mg_arr, float* __restrict__ enm)
{
  int bh = blockIdx.x; int b = bh>>3, h = bh&7;
  int lane = threadIdx.x;
  float bi = bif[h], bff = bif[8+h];
  float fl[24], gl[24];
  int l0 = lane*24;
  float s = 0.f;
  #pragma unroll
  for (int j=0;j<24;j++){
    int l = l0+j;
    float f = gates[((long)(b*1536+l))*16 + 8 + h] + bff;
    float ls = fminf(f,0.f) - log1pf(expf(-fabsf(f)));
    fl[j] = ls; s += ls;
  }
  float tot = s;
  for (int off=1; off<64; off<<=1){ float t = __shfl_up(s, off); if (lane>=off) s += t; }
  float fc = s - tot;
  float lm = -INFINITY;
  #pragma unroll
  for (int j=0;j<24;j++){
    int l = l0+j;
    fc += fl[j];
    fl[j] = fc;
    float ir = gates[((long)(b*1536+l))*16 + h] + bi;
    float g = expf(ir) - fc;
    gl[j] = g;
    lm = fmaxf(lm, g);
  }
  float im = lm;
  for (int off=1; off<64; off<<=1){ float t = __shfl_up(im, off); if (lane>=off) im = fmaxf(im,t); }
  float ex = __shfl_up(im, 1);
  if (lane==0) ex = -INFINITY;
  float rm = ex;
  #pragma unroll
  for (int j=0;j<24;j++){
    rm = fmaxf(rm, gl[j]);
    long idx = (long)bh*1536 + l0 + j;
    g_arr[idx] = gl[j];
    mg_arr[idx] = rm;
    enm[idx] = expf(-(fl[j] + rm));
  }
}

// ---------------- Q/K/V -> fragment-major global repack ----------------
// qf/kf: [bh][chunk][n16 2][kc 8][lane 64][8]; vf: [bh][chunk][tj 16][lane 64][8]
// K pre-scaled by 1/16 (exact in bf16).
__global__ __launch_bounds__(256) void repack_kernel(const u16* __restrict__ qkv,
        u16* __restrict__ qf, u16* __restrict__ kf, u16* __restrict__ vf)
{
  int bh = blockIdx.x, c = blockIdx.y;
  int b = bh>>3, h = bh&7;
  int tid = threadIdx.x;
  long rowb = (long)b*1536 + c*32;
  #pragma unroll
  for (int s4=0; s4<4; s4++){
    int s = s4*256 + tid;
    int n16 = s>>9, kc=(s>>6)&7, l=s&63, quad=l>>4, l15=l&15;
    const u16* src = qkv + (rowb + n16*16 + l15)*6144 + h*768 + kc*32 + quad*8;
    us8 q = *(const us8*)src;
    us8 k = *(const us8*)(src + 256);
    us8 ksc;
    #pragma unroll
    for (int j=0;j<8;j++) ksc[j] = f2bf(bf2f(k[j])*0.0625f);
    int tj = s>>6;     // 0..15
    us8 v;
    #pragma unroll
    for (int j=0;j<8;j++)
      v[j] = qkv[(rowb + quad*8 + j)*6144 + h*768 + 512 + tj*16 + l15];
    long dst = ((long)(bh*48+c))*8192 + (long)s*8;
    *(us8*)(qf+dst) = q;
    *(us8*)(kf+dst) = ksc;
    *(us8*)(vf+dst) = v;
  }
}

// ---------------- decayed attention: 4 waves share one 32-row o-tile, i-strided ----------------
// grid (16 bh, 48 otiles), 256 threads. Fragment-major coalesced global loads, barrier-free
// main loop; LDS tree-reduce at end.
__global__ __launch_bounds__(256,2) void attn_kernel(
    const u16* __restrict__ qf, const u16* __restrict__ kf, const u16* __restrict__ vf,
    const float* __restrict__ g_arr, const float* __restrict__ mg_arr,
    const float* __restrict__ enm,
    const float* __restrict__ hn_w, const float* __restrict__ skip,
    const float* __restrict__ qkf, const float* __restrict__ s2,
    u16* __restrict__ xm)
{
  __shared__ u16 pl[4][32][40];
  __shared__ float red[256*36];     // [col][row-pad36]
  __shared__ float redb[3][32];
  int tid = threadIdx.x;
  int lane = tid&63, wave = tid>>6, quad = lane>>4, l15 = lane&15;
  int bh = blockIdx.x, b = bh>>3, h = bh&7;
  int otile = 47 - blockIdx.y;               // heavy-first
  int ow0 = otile*32;
  // Q preload: fragment-major, coalesced
  const u16* qfb = qf + ((long)(bh*48+otile))*8192;
  us8 qreg[2][8];
  #pragma unroll
  for (int mt=0;mt<2;mt++)
    #pragma unroll
    for (int kc=0;kc<8;kc++)
      qreg[mt][kc] = *(const us8*)(qfb + mt*4096 + kc*512 + lane*8);
  float mg[2][4];
  #pragma unroll
  for (int mt=0;mt<2;mt++)
    #pragma unroll
    for (int r=0;r<4;r++)
      mg[mt][r] = mg_arr[(long)bh*1536 + ow0 + mt*16 + quad*4 + r];
  f32x4 accv[2][16] = {};
  float bs[2][4] = {};
  for (int it=wave; it<=otile; it+=4){
    int i0 = it*32;
    // S = Q K^T, K pre-scaled by 1/16
    const u16* kfb = kf + ((long)(bh*48+it))*8192;
    f32x4 sacc[2][2] = {};
    #pragma unroll
    for (int kc=0;kc<8;kc++){
      bf16x8 b0 = *(const bf16x8*)(kfb + kc*512 + lane*8);
      bf16x8 b1 = *(const bf16x8*)(kfb + 4096 + kc*512 + lane*8);
      sacc[0][0] = MFMA(asbf(qreg[0][kc]), b0, sacc[0][0]);
      sacc[0][1] = MFMA(asbf(qreg[0][kc]), b1, sacc[0][1]);
      sacc[1][0] = MFMA(asbf(qreg[1][kc]), b0, sacc[1][0]);
      sacc[1][1] = MFMA(asbf(qreg[1][kc]), b1, sacc[1][1]);
    }
    // P = mask * S * exp(g[i]-maxg[o])
    #pragma unroll
    for (int nt=0;nt<2;nt++){
      float gi = g_arr[(long)bh*1536 + i0 + nt*16 + l15];
      #pragma unroll
      for (int mt=0;mt<2;mt++)
        #pragma unroll
        for (int r=0;r<4;r++){
          int oi = ow0 + mt*16 + quad*4 + r;
          int ii = i0 + nt*16 + l15;
          float p = (ii <= oi) ? sacc[mt][nt][r]*__expf(gi - mg[mt][r]) : 0.f;
          bs[mt][r] += p;
          pl[wave][mt*16+quad*4+r][nt*16+l15] = f2bf(p);
        }
    }
    // H += P V (V^T fragments coalesced from global)
    const u16* vfb = vf + ((long)(bh*48+it))*8192;
    bf16x8 pa0 = *(const bf16x8*)&pl[wave][l15][quad*8];
    bf16x8 pa1 = *(const bf16x8*)&pl[wave][16+l15][quad*8];
    #pragma unroll
    for (int tj=0;tj<16;tj++){
      bf16x8 vb = *(const bf16x8*)(vfb + tj*512 + lane*8);
      accv[0][tj] = MFMA(pa0, vb, accv[0][tj]);
      accv[1][tj] = MFMA(pa1, vb, accv[1][tj]);
    }
  }
  // lane-reduce bsum
  #pragma unroll
  for (int mt=0;mt<2;mt++)
    #pragma unroll
    for (int r=0;r<4;r++)
      #pragma unroll
      for (int off=1; off<16; off<<=1) bs[mt][r] += __shfl_xor(bs[mt][r], off);
  // cross-wave tree reduction through LDS
  for (int w=1; w<4; w++){
    if (wave==w){
      #pragma unroll
      for (int mt=0;mt<2;mt++)
        #pragma unroll
        for (int tj=0;tj<16;tj++)
          *(f32x4*)&red[(tj*16+l15)*36 + mt*16 + quad*4] = accv[mt][tj];
      if (l15==0){
        #pragma unroll
        for (int mt=0;mt<2;mt++)
          #pragma unroll
          for (int r=0;r<4;r++)
            redb[w-1][mt*16+quad*4+r] = bs[mt][r];
      }
    }
    __syncthreads();
    if (wave==0){
      #pragma unroll
      for (int mt=0;mt<2;mt++)
        #pragma unroll
        for (int tj=0;tj<16;tj++)
          accv[mt][tj] += *(const f32x4*)&red[(tj*16+l15)*36 + mt*16 + quad*4];
      #pragma unroll
      for (int mt=0;mt<2;mt++)
        #pragma unroll
        for (int r=0;r<4;r++)
          bs[mt][r] += redb[w-1][mt*16+quad*4+r];
    }
    __syncthreads();
  }
  if (wave != 0) return;
  // epilogue: n = max(|bsum|, exp(-m)); h = acc/n; LN(hn_w); (h + skip*qk)*s2 -> xm
  long browg = (long)b*1536;
  #pragma unroll
  for (int mt=0;mt<2;mt++){
    #pragma unroll
    for (int r=0;r<4;r++){
      int row = ow0 + mt*16 + quad*4 + r;
      float s1 = 0.f, sq = 0.f;
      #pragma unroll
      for (int tj=0;tj<16;tj++){ float a = accv[mt][tj][r]; s1 += a; sq += a*a; }
      #pragma unroll
      for (int off=1; off<16; off<<=1){ s1 += __shfl_xor(s1,off); sq += __shfl_xor(sq,off); }
      float nv = fmaxf(fabsf(bs[mt][r]), enm[(long)bh*1536 + row]);
      float inv = 1.f/nv;
      float mu = s1*inv*(1.f/256.f);
      float var = sq*inv*inv*(1.f/256.f) - mu*mu;
      float rs = rsqrtf(var + 1e-5f);
      long rg = browg + row;
      #pragma unroll
      for (int tj=0;tj<16;tj++){
        int col = tj*16 + l15;
        int cc = h*256 + col;
        float y = (accv[mt][tj][r]*inv - mu)*rs*hn_w[col];
        float xv = (y + skip[cc]*qkf[rg*2048 + cc]) * s2[rg*2048 + cc];
        xm[rg*2048 + cc] = f2bf(xv);
      }
    }
  }
}

extern "C" void kernel_launch(void* const* d_in, const int* in_sizes, int n_in,
                              void* d_out, int out_size, void* d_ws, size_t ws_size,
                              hipStream_t stream)
{
  const float* x      = (const float*)d_in[0];
  const float* ln_w   = (const float*)d_in[1];
  const float* ln_b   = (const float*)d_in[2];
  const float* w1     = (const float*)d_in[3];
  const float* b1     = (const float*)d_in[4];
  const float* conv_w = (const float*)d_in[5];
  const float* conv_b = (const float*)d_in[6];
  const float* skip   = (const float*)d_in[7];
  const float* wqk    = (const float*)d_in[8];
  const float* bqk    = (const float*)d_in[9];
  const float* wv     = (const float*)d_in[10];
  const float* bv     = (const float*)d_in[11];
  const float* wif    = (const float*)d_in[12];
  const float* bif    = (const float*)d_in[13];
  const float* hn_w   = (const float*)d_in[14];
  const float* w2     = (const float*)d_in[15];
  const float* b2     = (const float*)d_in[16];
  float* out = (float*)d_out;

  char* p = (char*)d_ws;
  auto alloc = [&](size_t bytes)->void*{ void* r = (void*)p; p += (bytes + 255) & ~(size_t)255; return r; };
  u16* w1b  = (u16*)alloc((size_t)4194304*2);
  u16* w2b  = (u16*)alloc((size_t)2097152*2);
  u16* wifb = (u16*)alloc((size_t)98304*2);
  u16* cw2  = (u16*)alloc((size_t)4194304*2);
  u16* cw3  = (u16*)alloc((size_t)4194304*2);
  u16* wqkt = (u16*)alloc((size_t)1048576*2);
  u16* wvt  = (u16*)alloc((size_t)524288*2);
  u16* xn   = (u16*)alloc((size_t)3072*1024*2);
  u16* x1b  = (u16*)alloc((size_t)3072*2048*2);
  float* s2 = (float*)alloc((size_t)3072*2048*4);
  float* qkf= (float*)alloc((size_t)3072*2048*4);
  u16* qkb  = (u16*)alloc((size_t)3072*2048*2);
  u16* qkv  = (u16*)alloc((size_t)3072*6144*2);
  u16* qfb  = (u16*)alloc((size_t)16*48*8192*2);
  u16* kfb  = (u16*)alloc((size_t)16*48*8192*2);
  u16* vfb  = (u16*)alloc((size_t)16*48*8192*2);
  float* gates = (float*)alloc((size_t)3072*16*4);
  float* g_arr = (float*)alloc((size_t)16*1536*4);
  float* mg_arr= (float*)alloc((size_t)16*1536*4);
  float* enm   = (float*)alloc((size_t)16*1536*4);
  u16* xmb  = (u16*)alloc((size_t)3072*2048*2);
  if ((size_t)(p - (char*)d_ws) > ws_size) return;

  hipMemsetAsync(gates, 0, (size_t)3072*16*4, stream);
  prep_kernel<<<4096, 256, 0, stream>>>(w1, w2, wif, conv_w, wqk, wv,
                                        w1b, w2b, wifb, cw2, cw3, wqkt, wvt);
  ln_kernel<<<3072, 256, 0, stream>>>(x, ln_w, ln_b, xn);
  // y = LN(x) @ w1^T + b1 ; split -> x1 (bf16), s2 = silu(x2) (f32)
  gemm_bt<<<dim3(32,24,1), 256, 0, stream>>>(xn, 1024, 0, nullptr, w1b, 1024, 0, nullptr,
       1024, 1024, 0, b1, 0, 2, nullptr, 0, 0, x1b, 2048, 0, nullptr, s2);
  // conv merged: z=0: silu(x1_0@cw3^T+cb); z=1: silu(x1_0@cw2^T + x1_1@cw3^T + cb)
  gemm_bt<<<dim3(16,12,2), 256, 0, stream>>>(x1b, 2048, 0, x1b + (long)1536*2048,
       cw3, 2048, 0, cw2, 2048, 4096, 1, conv_b, 0, 3,
       qkf, 2048, (long)1536*2048, qkb, 2048, (long)1536*2048, nullptr, nullptr);
  // per-head q,k projection -> qkv[.., h*768 + 0..511]
  gemm_bt<<<dim3(4,24,8), 256, 0, stream>>>(qkb, 2048, 256, nullptr, wqkt, 256, 131072, nullptr,
       256, 256, 0, bqk, 512, 1, nullptr, 0, 0, qkv, 6144, 768, nullptr, nullptr);
  // per-head v projection -> qkv[.., h*768 + 512..767]
  gemm_bt<<<dim3(2,24,8), 256, 0, stream>>>(x1b, 2048, 256, nullptr, wvt, 256, 65536, nullptr,
       256, 256, 0, bv, 256, 1, nullptr, 0, 0, qkv + 512, 6144, 768, nullptr, nullptr);
  repack_kernel<<<dim3(16,48,1), 256, 0, stream>>>(qkv, qfb, kfb, vfb);
  gates_gemm<<<dim3(24,4,1), 256, 0, stream>>>(qkv, wifb, gates);
  scan_kernel<<<16, 64, 0, stream>>>(gates, bif, g_arr, mg_arr, enm);
  attn_kernel<<<dim3(16,48,1), 256, 0, stream>>>(qfb, kfb, vfb, g_arr, mg_arr, enm,
       hn_w, skip, qkf, s2, xmb);
  // out = xm @ w2^T + b2 + x
  gemm_bt<<<dim3(8,24,1), 256, 0, stream>>>(xmb, 2048, 0, nullptr, w2b, 2048, 0, nullptr,
       2048, 2048, 0, b2, 0, 4, out, 1024, 0, nullptr, 0, 0, x, nullptr);
}